// Round 2
// baseline (137.977 us; speedup 1.0000x reference)
//
#include <hip/hip_runtime.h>
#include <math.h>

// Problem constants (from reference setup_inputs)
constexpr int kB  = 32;
constexpr int kS  = 4096;
constexpr int kH  = 1024;
constexpr int kNC = 128;          // S-chunks per batch
constexpr int kCH = kS / kNC;     // 32 rows per chunk
constexpr int WPB = 4;            // waves per block (256 threads)

// One context row as held by one lane: float4 at h = 4*lane + 256*k, k=0..3
struct Row { float4 a, b, c, d; };

__device__ __forceinline__ Row load_row(const float4* __restrict__ p) {
  Row r; r.a = p[0]; r.b = p[64]; r.c = p[128]; r.d = p[192]; return r;
}

__device__ __forceinline__ float dot_row(const Row& w, const Row& q) {
  float s;
  s  = w.a.x*q.a.x + w.a.y*q.a.y + w.a.z*q.a.z + w.a.w*q.a.w;
  s += w.b.x*q.b.x + w.b.y*q.b.y + w.b.z*q.b.z + w.b.w*q.b.w;
  s += w.c.x*q.c.x + w.c.y*q.c.y + w.c.z*q.c.z + w.c.w*q.c.w;
  s += w.d.x*q.d.x + w.d.y*q.d.y + w.d.z*q.d.z + w.d.w*q.d.w;
  return s;
}

#define AXPY4(acc4, p, w4) \
  acc4.x = fmaf(p, w4.x, acc4.x); acc4.y = fmaf(p, w4.y, acc4.y); \
  acc4.z = fmaf(p, w4.z, acc4.z); acc4.w = fmaf(p, w4.w, acc4.w);

#define SCALE4(acc4, s) \
  acc4.x *= s; acc4.y *= s; acc4.z *= s; acc4.w *= s;

// Online-softmax update for a PAIR of rows. Exact defer-max: rescale only
// when the pair max exceeds the running max (wave-uniform branch; when it
// doesn't, sc == exp(0) == 1 exactly, so skipping is exact).
__device__ __forceinline__ void pair_update(float d0, float d1,
                                            const Row& w0, const Row& w1,
                                            float& m, float& l, Row& acc) {
  const float dmax = fmaxf(d0, d1);
  if (dmax > m) {
    const float sc = __expf(m - dmax);
    m = dmax;
    l *= sc;
    SCALE4(acc.a, sc); SCALE4(acc.b, sc); SCALE4(acc.c, sc); SCALE4(acc.d, sc);
  }
  const float p0 = __expf(d0 - m);
  const float p1 = __expf(d1 - m);
  l += p0 + p1;
  AXPY4(acc.a, p0, w0.a); AXPY4(acc.a, p1, w1.a);
  AXPY4(acc.b, p0, w0.b); AXPY4(acc.b, p1, w1.b);
  AXPY4(acc.c, p0, w0.c); AXPY4(acc.c, p1, w1.c);
  AXPY4(acc.d, p0, w0.d); AXPY4(acc.d, p1, w1.d);
}

// ---------------------------------------------------------------------------
// Pass 1: one wave per (batch, chunk). Flash-style online softmax over the
// chunk's 32 context rows, processed in pairs with a 4-row register rotation
// (pair in compute, pair in flight). Each row read ONCE (K and V).
// ---------------------------------------------------------------------------
__global__ __launch_bounds__(256, 4) void attn_pass1(
    const float* __restrict__ q,      // [B, H]
    const float* __restrict__ ctx,    // [B, S, H]
    float* __restrict__ scores,       // [B, S]   raw logits
    float* __restrict__ pm,           // [B*NC]
    float* __restrict__ pl,           // [B*NC]
    float* __restrict__ pacc)         // [B*NC, H]
{
  const int lane = threadIdx.x & 63;
  const int wid  = threadIdx.x >> 6;
  const int wave = blockIdx.x * WPB + wid;   // 0 .. B*NC-1
  const int b    = wave / kNC;
  const int c    = wave % kNC;

  const float4* qp = reinterpret_cast<const float4*>(q + (size_t)b * kH) + lane;
  const Row Q = load_row(qp);

  const float4* cp =
      reinterpret_cast<const float4*>(ctx + ((size_t)b * kS + (size_t)c * kCH) * kH) + lane;

  float m = -3.0e38f, l = 0.0f;
  Row acc; acc.a = make_float4(0.f,0.f,0.f,0.f); acc.b = acc.a; acc.c = acc.a; acc.d = acc.a;
  float myscore = 0.0f;

  // prologue: rows 0..3 in flight
  Row RA = load_row(cp + 0 * 256);
  Row RB = load_row(cp + 1 * 256);
  Row RC = load_row(cp + 2 * 256);
  Row RD = load_row(cp + 3 * 256);

  #pragma unroll
  for (int r = 0; r < kCH; r += 4) {
    // ---- phase 1: rows r, r+1 (RA, RB) ----
    {
      float d0 = dot_row(RA, Q), d1 = dot_row(RB, Q);
      #pragma unroll
      for (int off = 32; off >= 1; off >>= 1) {
        d0 += __shfl_xor(d0, off, 64);
        d1 += __shfl_xor(d1, off, 64);
      }
      if (lane == r)     myscore = d0;
      if (lane == r + 1) myscore = d1;
      pair_update(d0, d1, RA, RB, m, l, acc);
      if (r + 4 < kCH) {
        RA = load_row(cp + (size_t)(r + 4) * 256);
        RB = load_row(cp + (size_t)(r + 5) * 256);
      }
    }
    // ---- phase 2: rows r+2, r+3 (RC, RD) ----
    {
      float d0 = dot_row(RC, Q), d1 = dot_row(RD, Q);
      #pragma unroll
      for (int off = 32; off >= 1; off >>= 1) {
        d0 += __shfl_xor(d0, off, 64);
        d1 += __shfl_xor(d1, off, 64);
      }
      if (lane == r + 2) myscore = d0;
      if (lane == r + 3) myscore = d1;
      pair_update(d0, d1, RC, RD, m, l, acc);
      if (r + 6 < kCH) {
        RC = load_row(cp + (size_t)(r + 6) * 256);
        RD = load_row(cp + (size_t)(r + 7) * 256);
      }
    }
  }

  // epilogue: coalesced stores
  if (lane < kCH) scores[(size_t)b * kS + (size_t)c * kCH + lane] = myscore;
  if (lane == 0) { pm[wave] = m; pl[wave] = l; }
  float4* pap = reinterpret_cast<float4*>(pacc + (size_t)wave * kH) + lane;
  pap[0] = acc.a; pap[64] = acc.b; pap[128] = acc.c; pap[192] = acc.d;
}

// ---------------------------------------------------------------------------
// Pass 2: grid (B, 9). Every block recomputes global (m_g, inv) from the 128
// chunk partials. Blocks by=0..7 each combine one 128-wide h slice of the
// acc partials (float4 loads, unroll 16, 8 i-stripes combined via LDS) and
// write out = tanh(acc*inv). Block by=8 normalizes raw logits into attn.
// d_out layout: [out (B*H floats)] ++ [attn (B*S floats)]
// ---------------------------------------------------------------------------
__global__ __launch_bounds__(256) void attn_pass2(
    const float* __restrict__ scores,
    const float* __restrict__ pm,
    const float* __restrict__ pl,
    const float* __restrict__ pacc,
    float* __restrict__ out)
{
  const int b  = blockIdx.x;
  const int by = blockIdx.y;
  const int t  = threadIdx.x;

  __shared__ float red[256];
  __shared__ float wgt[kNC];
  __shared__ float4 sh4[8][32];

  // global max over this batch's chunk maxima
  const float mi = (t < kNC) ? pm[b * kNC + t] : -3.0e38f;
  red[t] = mi;
  __syncthreads();
  #pragma unroll
  for (int o = 128; o >= 1; o >>= 1) {
    if (t < o) red[t] = fmaxf(red[t], red[t + o]);
    __syncthreads();
  }
  const float m_g = red[0];
  __syncthreads();

  // per-chunk rescale weights + global denom
  float li = 0.0f;
  if (t < kNC) {
    const float wi = __expf(mi - m_g);
    wgt[t] = wi;
    li = pl[b * kNC + t] * wi;
  }
  red[t] = li;
  __syncthreads();
  #pragma unroll
  for (int o = 128; o >= 1; o >>= 1) {
    if (t < o) red[t] += red[t + o];
    __syncthreads();
  }
  const float inv = 1.0f / red[0];
  __syncthreads();

  if (by < 8) {
    // combine acc partials for h in [by*128, by*128+128)
    const int h4     = t & 31;   // float4 index within the slice
    const int stripe = t >> 5;   // 8 i-stripes
    const float4* base =
        reinterpret_cast<const float4*>(pacc + ((size_t)(b * kNC + stripe)) * kH + by * 128) + h4;
    const size_t istep = (size_t)8 * (kH / 4);  // i += 8, in float4 units

    float4 s = make_float4(0.f, 0.f, 0.f, 0.f);
    #pragma unroll 16
    for (int k = 0; k < 16; ++k) {
      const float w = wgt[stripe + 8 * k];
      const float4 v = base[(size_t)k * istep];
      s.x = fmaf(w, v.x, s.x); s.y = fmaf(w, v.y, s.y);
      s.z = fmaf(w, v.z, s.z); s.w = fmaf(w, v.w, s.w);
    }
    sh4[stripe][h4] = s;
    __syncthreads();

    if (t < 32) {
      float4 r = sh4[0][t];
      #pragma unroll
      for (int i = 1; i < 8; ++i) {
        const float4 v = sh4[i][t];
        r.x += v.x; r.y += v.y; r.z += v.z; r.w += v.w;
      }
      r.x = tanhf(r.x * inv); r.y = tanhf(r.y * inv);
      r.z = tanhf(r.z * inv); r.w = tanhf(r.w * inv);
      reinterpret_cast<float4*>(out + (size_t)b * kH + by * 128)[t] = r;
    }
  } else {
    // normalize logits -> attn (float4, coalesced)
    const float4* sb = reinterpret_cast<const float4*>(scores + (size_t)b * kS);
    float4* ab = reinterpret_cast<float4*>(out + (size_t)kB * kH + (size_t)b * kS);
    #pragma unroll
    for (int k = 0; k < kS / 4 / 256; ++k) {
      const int i = k * 256 + t;
      float4 v = sb[i];
      v.x = __expf(v.x - m_g) * inv; v.y = __expf(v.y - m_g) * inv;
      v.z = __expf(v.z - m_g) * inv; v.w = __expf(v.w - m_g) * inv;
      ab[i] = v;
    }
  }
}

extern "C" void kernel_launch(void* const* d_in, const int* in_sizes, int n_in,
                              void* d_out, int out_size, void* d_ws, size_t ws_size,
                              hipStream_t stream) {
  const float* q   = (const float*)d_in[0];   // output: (B,1,H) fp32 — the query
  const float* ctx = (const float*)d_in[1];   // context: (B,S,H) fp32
  float* out = (float*)d_out;
  float* ws  = (float*)d_ws;

  // workspace layout (floats): scores[B*S] | pm[B*NC] | pl[B*NC] | pacc[B*NC*H]
  float* scores = ws;
  float* pm     = scores + (size_t)kB * kS;
  float* pl     = pm + kB * kNC;
  float* pacc   = pl + kB * kNC;   // offset 139264 floats -> 16B aligned

  attn_pass1<<<dim3(kB * kNC / WPB), 256, 0, stream>>>(q, ctx, scores, pm, pl, pacc);
  attn_pass2<<<dim3(kB, 9), 256, 0, stream>>>(scores, pm, pl, pacc, out);
}